// Round 9
// baseline (47.492 us; speedup 1.0000x reference)
//
#include <hip/hip_runtime.h>
#include <stdint.h>

// Spatial transformer: batched dense-displacement trilinear warp, LDS-staged.
// vol: [B=2, D=128, H=192, W=192, 1] f32
// trf: [B=2, D=128, H=192, W=192, 3] f32 (displacement along z,y,x)
// out: [B=2, D=128, H=192, W=192, 1] f32

#define BD 128
#define BH 192
#define BW 192
#define DHW (BD*BH*BW)
#define NB 2

// output tile per block: 16 x * 8 y * 8 z = 1024 voxels, 256 thr * 1 quad
#define TX 16
#define TY 8
#define TZ 8
#define NTX (BW/TX)                 // 12
#define NTY (BH/TY)                 // 24
#define NTZ (BD/TZ)                 // 16
#define NBLK (NTX*NTY*NTZ*NB)       // 9216  (% 8 == 0)
#define NXCD 8

// staged window: x 36 [tx-8..tx+27], y 16 [ty-4..ty+11], z 16 [tz-4..tz+11].
// pitch 36 = 9 chunks of 4 floats: rows tile LDS contiguously (chunk f -> float 4f),
// so width-16 global_load_lds stays lane-linear, AND bank = (xi + 4*yi) % 32
// mixes y into the bank index (pitch-32 had bank = xi only -> 8.7M conflict cyc).
#define SXW 36
#define SYW 16
#define SZW 16
#define SLAB (SXW*SYW)              // 576 floats per z-slab
#define LDSF (SLAB*SZW)             // 9216 floats = 36864 B -> 4 blocks/CU
#define NCHUNK (LDSF/4)             // 2304 = 9 * 256 exactly

typedef float f4v __attribute__((ext_vector_type(4)));

__global__ __launch_bounds__(256, 4) void st_warp_kernel(
    const float* __restrict__ vol,
    const float* __restrict__ trf,
    float* __restrict__ out)
{
    __shared__ __align__(16) float lds[LDSF];

    // XCD-chunked swizzle: each XCD gets a contiguous chunk of 1152 blocks
    const int bid = blockIdx.x;
    const int swz = (bid % NXCD) * (NBLK / NXCD) + bid / NXCD;
    int tmp = swz;
    const int txi = tmp % NTX; tmp /= NTX;
    const int tyi = tmp % NTY; tmp /= NTY;
    const int tzi = tmp % NTZ; tmp /= NTZ;
    const int b   = tmp;
    const int tx = txi*TX, ty = tyi*TY, tz = tzi*TZ;

    const int sx = min(max(tx - 8, 0), BW - SXW);   // multiple of 4 -> 16B aligned
    const int sy = min(max(ty - 4, 0), BH - SYW);
    const int sz = min(max(tz - 4, 0), BD - SZW);

    const int tid = (int)threadIdx.x;
    const float* volb = vol + (size_t)b * DHW;

    // ---------- phase 1: ISSUE vol staging (width-16, 9 iters, no tail) ---------
    // chunk f: row r = f/9 (zi=r>>4, yi=r&15), col c = f%9, global x = sx + 4c.
    // LDS dest = float 4f (rows are 9 chunks -> contiguous tiling).
#pragma unroll
    for (int it = 0; it < 9; ++it) {
        const int f = tid + it*256;
        const int r = f / 9;                 // compiler magic-div
        const int c = f - r*9;
        const int zi = r >> 4;
        const int yi = r & 15;
        const float* g = volb + ((size_t)((sz+zi)*BH + (sy+yi)))*BW + sx + c*4;
        __builtin_amdgcn_global_load_lds(
            (const __attribute__((address_space(1))) void*)g,
            (__attribute__((address_space(3))) void*)&lds[f*4],
            16, 0, 0);
    }

    // ---------- phase 2: trf direct loads -> regs (overlap staging latency) -----
    const int xq = tid & 3;
    const int yb = (tid >> 2) & 7;
    const int zb = tid >> 5;
    const int Y  = ty + yb;
    const int Z  = tz + zb;
    const int Xb = tx + xq*4;
    const f4v* trf4 = (const f4v*)trf;
    const size_t rowf4 = ((size_t)((b*BD + Z)*BH + Y)*BW + tx) * 3 / 4;
    const f4v tA = trf4[rowf4 + 3*xq + 0];
    const f4v tB = trf4[rowf4 + 3*xq + 1];
    const f4v tC = trf4[rowf4 + 3*xq + 2];

    __syncthreads();                            // drains vmcnt (staging) + lgkm

    // ---------- phase 3: sample 4 voxels from LDS (rare global fallback) --------
    const float dzs[4] = {tA.x, tA.w, tB.z, tC.y};
    const float dys[4] = {tA.y, tB.x, tB.w, tC.z};
    const float dxs[4] = {tA.z, tB.y, tC.x, tC.w};
    float res[4];
#pragma unroll
    for (int jj = 0; jj < 4; ++jj) {
        float cz = fminf(fmaxf((float)Z + dzs[jj], 0.f), (float)(BD-1));
        float cy = fminf(fmaxf((float)Y + dys[jj], 0.f), (float)(BH-1));
        float cx = fminf(fmaxf((float)(Xb+jj) + dxs[jj], 0.f), (float)(BW-1));
        float fz = floorf(cz), fy = floorf(cy), fx = floorf(cx);
        int z0 = (int)fz, y0 = (int)fy, x0 = (int)fx;
        int z1 = min(z0+1, BD-1);
        int y1 = min(y0+1, BH-1);
        int x1 = min(x0+1, BW-1);
        float wz = cz - fz, wy = cy - fy, wx = cx - fx;
        float v000,v001,v010,v011,v100,v101,v110,v111;
        bool inwin = (x0 >= sx) & (x1 <= sx+SXW-1) & (y0 >= sy) & (y1 <= sy+SYW-1)
                   & (z0 >= sz) & (z1 <= sz+SZW-1);
        if (inwin) {
            const int xi  = x0 - sx;
            const int xiA = min(xi, SXW-2);     // x==191 edge: read (34,35), select
            const bool lo = xi < SXW-1;
            const int rA = (z0 - sz)*SLAB + (y0 - sy)*SXW + xiA;
            const int rB = (z0 - sz)*SLAB + (y1 - sy)*SXW + xiA;
            const int rC = (z1 - sz)*SLAB + (y0 - sy)*SXW + xiA;
            const int rD = (z1 - sz)*SLAB + (y1 - sy)*SXW + xiA;
            float a00 = lds[rA], b00 = lds[rA+1];
            float a01 = lds[rB], b01 = lds[rB+1];
            float a10 = lds[rC], b10 = lds[rC+1];
            float a11 = lds[rD], b11 = lds[rD+1];
            v000 = lo ? a00 : b00;  v001 = b00;
            v010 = lo ? a01 : b01;  v011 = b01;
            v100 = lo ? a10 : b10;  v101 = b10;
            v110 = lo ? a11 : b11;  v111 = b11;
        } else {
            const float* p00 = volb + ((size_t)z0*BH + y0)*BW;
            const float* p01 = volb + ((size_t)z0*BH + y1)*BW;
            const float* p10 = volb + ((size_t)z1*BH + y0)*BW;
            const float* p11 = volb + ((size_t)z1*BH + y1)*BW;
            v000 = p00[x0]; v001 = p00[x1];
            v010 = p01[x0]; v011 = p01[x1];
            v100 = p10[x0]; v101 = p10[x1];
            v110 = p11[x0]; v111 = p11[x1];
        }
        float c00 = v000 + wx*(v001-v000);
        float c01 = v010 + wx*(v011-v010);
        float c10 = v100 + wx*(v101-v100);
        float c11 = v110 + wx*(v111-v110);
        float c0  = c00 + wy*(c01-c00);
        float c1  = c10 + wy*(c11-c10);
        res[jj]   = c0 + wz*(c1-c0);
    }
    f4v r = {res[0], res[1], res[2], res[3]};
    const size_t of4 = ((size_t)((b*BD + Z)*BH + Y)*BW + Xb) / 4;
    __builtin_nontemporal_store(r, &((f4v*)out)[of4]);  // no-allocate: avoid 2x partial-line writeback
}

extern "C" void kernel_launch(void* const* d_in, const int* in_sizes, int n_in,
                              void* d_out, int out_size, void* d_ws, size_t ws_size,
                              hipStream_t stream) {
    const float* vol = (const float*)d_in[0];
    const float* trf = (const float*)d_in[1];
    float* out = (float*)d_out;

    st_warp_kernel<<<dim3(NBLK), dim3(256), 0, stream>>>(vol, trf, out);
}

// Round 11
// 42.230 us; speedup vs baseline: 1.1246x; 1.1246x over previous
//
#include <hip/hip_runtime.h>
#include <stdint.h>

// Spatial transformer: batched dense-displacement trilinear warp.
// z-marching ring-buffer LDS pipeline (issue-early / wait-late).
// vol: [B=2, D=128, H=192, W=192, 1] f32
// trf: [B=2, D=128, H=192, W=192, 3] f32 (displacement along z,y,x)
// out: [B=2, D=128, H=192, W=192, 1] f32

#define BD 128
#define BH 192
#define BW 192
#define DHW (BD*BH*BW)
#define NB 2

// xy tile 16x8, block marches 4 z-steps of 8 -> 4096 voxels/block
#define TX 16
#define TY 8
#define NTX (BW/TX)                 // 12
#define NTY (BH/TY)                 // 24
#define NZB 4                       // z-chunks (of 32) per volume
#define NSTEPB 4                    // steps per block
#define NBLK (NTX*NTY*NZB*NB)       // 2304 (%8==0); 9 blocks/CU at 3-deep = 3 rounds
#define NXCD 8

// staged slab: x 32 [tx-8..tx+23] * y 16 [ty-4..ty+11], one z  = 512 floats = 2KB
// ring of 24 slabs (z mod 24) = 48KB -> 3 blocks/CU.
// alive at step k: window [8k-4, 8k+11] + prefetch [8k+12, 8k+19] = 24 distinct mod 24;
// prefetch slots == slots of slabs [8k-12, 8k-5], retired when the window advanced.
#define SXW 32
#define SYW 16
#define SLAB (SXW*SYW)              // 512 floats
#define RING 24
#define LDSF (RING*SLAB)            // 12288 floats = 49152 B

typedef float f4v __attribute__((ext_vector_type(4)));

// r9 bug: hand magic 5461 gave mod24(24)=24 (ring overflow). Let the compiler
// emit the exact magic for an unsigned constant divisor.
__device__ __forceinline__ int mod24(int z) {
    return (int)((unsigned)z % 24u);
}

__global__ __launch_bounds__(256, 3) void st_warp_kernel(
    const float* __restrict__ vol,
    const float* __restrict__ trf,
    float* __restrict__ out)
{
    __shared__ __align__(16) float lds[LDSF];

    // XCD-chunked swizzle (2304 % 8 == 0 -> bijective)
    const int bid = blockIdx.x;
    const int swz = (bid % NXCD) * (NBLK / NXCD) + bid / NXCD;
    int t = swz;
    const int txi = t % NTX; t /= NTX;
    const int tyi = t % NTY; t /= NTY;
    const int kzb = t % NZB; t /= NZB;
    const int b   = t;
    const int tx = txi*TX, ty = tyi*TY;
    const int zA = kzb * (NSTEPB*8);            // first output z of this block

    const int sx = min(max(tx - 8, 0), BW - SXW);   // multiple of 4 -> 16B aligned
    const int sy = min(max(ty - 4, 0), BH - SYW);

    const int tid = (int)threadIdx.x;
    const float* volb = vol + (size_t)b * DHW;

    // thread's voxel-quad within a step: x = Xb..Xb+3, y = Y, z = zstep + zb
    const int xq = tid & 3;
    const int yb = (tid >> 2) & 7;
    const int zb = tid >> 5;
    const int Y  = ty + yb;
    const int Xb = tx + xq*4;
    const f4v* trf4 = (const f4v*)trf;

    // ---- stage nslab slabs [zfirst, zfirst+nslab) into ring slots (z mod 24) ----
    // chunk f (16B): slab f>>7, within-slab chunk s=f&127 (yi=s>>3, c=s&7).
    // wave-runs of 64 chunks are 64-aligned -> never straddle a 128-chunk slab
    // -> slot uniform per wave -> LDS dest stays base + lane*16 (linear, required).
    auto stage = [&](int zfirst, int nslab) {
        const int nch = nslab << 7;
        for (int it = 0; it*256 < nch; ++it) {
            const int f = tid + it*256;
            if (f < nch) {
                const int z  = zfirst + (f >> 7);
                const int s  = f & 127;
                const int yi = s >> 3;
                const int c  = s & 7;
                const int slot = mod24(z);
                const float* g = volb + ((size_t)(z*BH + sy + yi))*BW + sx + (c<<2);
                __builtin_amdgcn_global_load_lds(
                    (const __attribute__((address_space(1))) void*)g,
                    (__attribute__((address_space(3))) void*)&lds[(slot<<9) + (s<<2)],
                    16, 0, 0);
            }
        }
    };

    auto load_trf = [&](int ZS, f4v& TA, f4v& TB, f4v& TC) {
        const size_t rowf4 = ((size_t)((b*BD + ZS + zb)*BH + Y)*BW + tx) * 3 / 4;
        TA = trf4[rowf4 + 3*xq + 0];
        TB = trf4[rowf4 + 3*xq + 1];
        TC = trf4[rowf4 + 3*xq + 2];
    };

    // ---- compute one step: 4 voxels at z = ZS + zb, from ring-resident slabs ----
    auto compute = [&](int ZS, f4v tA, f4v tB, f4v tC) {
        const int Z   = ZS + zb;
        const int wlo = max(0, ZS - 4);
        const int whi = min(BD - 1, ZS + 11);
        const float dzs[4] = {tA.x, tA.w, tB.z, tC.y};
        const float dys[4] = {tA.y, tB.x, tB.w, tC.z};
        const float dxs[4] = {tA.z, tB.y, tC.x, tC.w};
        float res[4];
#pragma unroll
        for (int jj = 0; jj < 4; ++jj) {
            float cz = fminf(fmaxf((float)Z + dzs[jj], 0.f), (float)(BD-1));
            float cy = fminf(fmaxf((float)Y + dys[jj], 0.f), (float)(BH-1));
            float cx = fminf(fmaxf((float)(Xb+jj) + dxs[jj], 0.f), (float)(BW-1));
            float fz = floorf(cz), fy = floorf(cy), fx = floorf(cx);
            int z0 = (int)fz, y0 = (int)fy, x0 = (int)fx;
            int z1 = min(z0+1, BD-1);
            int y1 = min(y0+1, BH-1);
            int x1 = min(x0+1, BW-1);
            float wz = cz - fz, wy = cy - fy, wx = cx - fx;
            float v000,v001,v010,v011,v100,v101,v110,v111;
            bool inwin = (x0 >= sx) & (x1 <= sx+SXW-1) & (y0 >= sy) & (y1 <= sy+SYW-1)
                       & (z0 >= wlo) & (z1 <= whi);
            if (inwin) {
                const int xi  = x0 - sx;
                const int xiA = min(xi, SXW-2);     // x==191 edge: read pair, select
                const bool lo = xi < SXW-1;
                int sl0 = mod24(z0);
                int sl1 = sl0 + 1;
                sl1 = (sl1 == RING) ? 0 : sl1;
                sl1 = (z1 == z0) ? sl0 : sl1;       // z clamped at top edge
                const int yt0 = (y0 - sy) << 5, yt1 = (y1 - sy) << 5;
                const int rA = (sl0<<9) + yt0 + xiA;
                const int rB = (sl0<<9) + yt1 + xiA;
                const int rC = (sl1<<9) + yt0 + xiA;
                const int rD = (sl1<<9) + yt1 + xiA;
                float a00 = lds[rA], b00 = lds[rA+1];
                float a01 = lds[rB], b01 = lds[rB+1];
                float a10 = lds[rC], b10 = lds[rC+1];
                float a11 = lds[rD], b11 = lds[rD+1];
                v000 = lo ? a00 : b00;  v001 = b00;
                v010 = lo ? a01 : b01;  v011 = b01;
                v100 = lo ? a10 : b10;  v101 = b10;
                v110 = lo ? a11 : b11;  v111 = b11;
            } else {
                const float* p00 = volb + ((size_t)z0*BH + y0)*BW;
                const float* p01 = volb + ((size_t)z0*BH + y1)*BW;
                const float* p10 = volb + ((size_t)z1*BH + y0)*BW;
                const float* p11 = volb + ((size_t)z1*BH + y1)*BW;
                v000 = p00[x0]; v001 = p00[x1];
                v010 = p01[x0]; v011 = p01[x1];
                v100 = p10[x0]; v101 = p10[x1];
                v110 = p11[x0]; v111 = p11[x1];
            }
            float c00 = v000 + wx*(v001-v000);
            float c01 = v010 + wx*(v011-v010);
            float c10 = v100 + wx*(v101-v100);
            float c11 = v110 + wx*(v111-v110);
            float c0  = c00 + wy*(c01-c00);
            float c1  = c10 + wy*(c11-c10);
            res[jj]   = c0 + wz*(c1-c0);
        }
        f4v r = {res[0], res[1], res[2], res[3]};
        const size_t of4 = ((size_t)((b*BD + Z)*BH + Y)*BW + Xb) / 4;
        __builtin_nontemporal_store(r, &((f4v*)out)[of4]);  // no-allocate store
    };

    // ---------------- pipeline ----------------
    f4v A0,B0,C0, A1,B1,C1;
    // prologue: first window [max(0,zA-4), zA+11] + trf for step 0
    stage(max(0, zA - 4), (zA == 0) ? 12 : 16);
    load_trf(zA, A0, B0, C0);
    __syncthreads();

#pragma unroll
    for (int kk = 0; kk < NSTEPB; kk += 2) {
        // even step: prefetch next slabs+trf (for step kk+1), compute with set0
        {
            const int zc = zA + kk*8;
            const int zn = zc + 12;
            if (zn < BD) stage(zn, min(8, BD - zn));
            load_trf(zc + 8, A1, B1, C1);          // kk+1 < NSTEPB always
            compute(zc, A0, B0, C0);
            __syncthreads();
        }
        // odd step: prefetch only if a step kk+2 exists (don't stage for the
        // next block -- that was 20% wasted staging traffic), compute with set1
        {
            const int zc = zA + kk*8 + 8;
            const int zn = zc + 12;
            if (kk + 2 < NSTEPB && zn < BD) stage(zn, min(8, BD - zn));
            if (kk + 2 < NSTEPB) load_trf(zc + 8, A0, B0, C0);
            compute(zc, A1, B1, C1);
            __syncthreads();
        }
    }
}

extern "C" void kernel_launch(void* const* d_in, const int* in_sizes, int n_in,
                              void* d_out, int out_size, void* d_ws, size_t ws_size,
                              hipStream_t stream) {
    const float* vol = (const float*)d_in[0];
    const float* trf = (const float*)d_in[1];
    float* out = (float*)d_out;

    st_warp_kernel<<<dim3(NBLK), dim3(256), 0, stream>>>(vol, trf, out);
}